// Round 25
// baseline (65.194 us; speedup 1.0000x reference)
//
#include <hip/hip_runtime.h>

// Head forward: q=x@Wq, k=x@Wk, v=x@Wv; out = softmax(causal(q k^T / 32)) @ v
// B=8 T=2048 C=1024 H=128. Inputs f32, output f32, internal bf16 MFMA.
// K and V are stored in FRAGMENT-MAJOR order (16B chunk = (frag)*64 + lane).
// W is stored in Wt2 fragment-major order.
// qkv v24 (depth-3 staging, counted vmcnt). attn v25: direct-L2 with
// COMPILER-PROOF counted-vmcnt pipeline — explicit vmcnt(8) after issuing
// K(s+4) guarantees K(s)/V(s) are in registers before the body, while
// K(s+4) stays in flight; V(s+4) issued after PV. No compiler-placed waits.

typedef __attribute__((ext_vector_type(8))) short short8;
typedef __attribute__((ext_vector_type(4))) float f32x4;

typedef const __attribute__((address_space(1))) unsigned int* gas_u32p;
typedef __attribute__((address_space(3))) unsigned int* las_u32p;

static __device__ __forceinline__ unsigned short f2bf(float f) {
  unsigned int u = __float_as_uint(f);
  u += 0x7FFF + ((u >> 16) & 1);      // round-to-nearest-even
  return (unsigned short)(u >> 16);
}

// ---------------- Kernel 0: Wt2 fragment-major weight transpose+convert.
__global__ void wtrans_kernel(const float* __restrict__ Wq,
                              const float* __restrict__ Wk,
                              const float* __restrict__ Wv,
                              unsigned short* __restrict__ Wt) {
  int idx = blockIdx.x * blockDim.x + threadIdx.x;   // 0 .. 3*128*1024-1
  int C  = idx >> 3;
  int e  = idx & 7;
  int l  = C & 63;
  int t1 = C >> 6;
  int kh = t1 & 1;
  int t2 = t1 >> 1;
  int w  = t2 % 3;
  int t3 = t2 / 3;
  int wave = t3 & 7;
  int kt   = t3 >> 3;
  int n = wave * 16 + (l & 15);
  int k = kt * 64 + kh * 32 + (l >> 4) * 8 + e;
  const float* W = (w == 0) ? Wq : (w == 1) ? Wk : Wv;
  Wt[idx] = f2bf(W[k * 128 + n]);
}

// ---------------- Kernel 1: fused QKV GEMM (BM=64, grid 256, depth-3).
__global__ __launch_bounds__(512) void qkv_kernel(
    const float* __restrict__ x,            // [16384][1024] f32
    const unsigned short* __restrict__ Wt,  // Wt2 fragment-major bf16
    unsigned short* __restrict__ q,         // [16384][128] bf16 (row-major)
    unsigned short* __restrict__ kb,        // [256 blk][8192] bf16 fragment-major
    unsigned short* __restrict__ vt)        // [8][32 blk][8192] bf16 fragment-major
{
  __shared__ float xl[4][4096];         // 4 x 16KB x-tiles, fragment-major
  const int tid  = threadIdx.x;
  const int lane = tid & 63;
  const int wave = tid >> 6;            // 0..7
  const int m0   = blockIdx.x * 64;
  const int lr   = lane & 15;

  f32x4 acc[4][3];
  #pragma unroll
  for (int i = 0; i < 4; ++i)
    #pragma unroll
    for (int w = 0; w < 3; ++w) acc[i][w] = (f32x4){0.f, 0.f, 0.f, 0.f};

  int srow[2], skq[2];
  #pragma unroll
  for (int i = 0; i < 2; ++i) {
    int c  = i * 512 + tid;
    int ln = c & 63;
    int g  = c >> 6;
    srow[i] = (g >> 2) * 16 + (ln & 15);
    skq[i]  = ((g >> 1) & 1) * 8 + (ln >> 4) * 2 + (g & 1);
  }

  #define QSTAGE(KT, BUF)                                                        \
    do {                                                                         \
      _Pragma("unroll")                                                          \
      for (int i = 0; i < 2; ++i) {                                              \
        const float* gsrc = x + (size_t)(m0 + srow[i]) * 1024 + (KT) * 64 + skq[i] * 4; \
        __builtin_amdgcn_global_load_lds((gas_u32p)gsrc,                         \
            (las_u32p)&xl[BUF][(i * 512 + tid) * 4], 16, 0, 0);                  \
      }                                                                          \
    } while (0)

  const unsigned short* w2base = Wt + wave * 3072 + lane * 8;

  #define WLOAD(KT, DST)                                                         \
    do {                                                                         \
      _Pragma("unroll")                                                          \
      for (int w = 0; w < 3; ++w) {                                              \
        DST[w][0] = *reinterpret_cast<const short8*>(w2base + (KT) * 24576 + w * 1024);       \
        DST[w][1] = *reinterpret_cast<const short8*>(w2base + (KT) * 24576 + w * 1024 + 512); \
      }                                                                          \
    } while (0)

  short8 wbuf[2][3][2];

  WLOAD(0, wbuf[0]);
  QSTAGE(0, 0);
  QSTAGE(1, 1);
  QSTAGE(2, 2);

  #pragma unroll
  for (int kt = 0; kt < 16; ++kt) {
    if (kt < 15) WLOAD(kt + 1, wbuf[(kt + 1) & 1]);
    if (kt < 13) QSTAGE(kt + 3, (kt + 3) & 3);
    if (kt < 13)      asm volatile("s_waitcnt vmcnt(10)" ::: "memory");
    else if (kt < 14) asm volatile("s_waitcnt vmcnt(8)"  ::: "memory");
    else if (kt < 15) asm volatile("s_waitcnt vmcnt(6)"  ::: "memory");
    else              asm volatile("s_waitcnt vmcnt(0)"  ::: "memory");
    __builtin_amdgcn_sched_barrier(0);
    __builtin_amdgcn_s_barrier();       // single barrier per step

    short8 af[4][2];
    #pragma unroll
    for (int mf = 0; mf < 4; ++mf)
      #pragma unroll
      for (int kh = 0; kh < 2; ++kh) {
        const float* basep = &xl[kt & 3][((mf * 2 + kh) * 2) * 256 + lane * 4];
        f32x4 h0 = *reinterpret_cast<const f32x4*>(basep);
        f32x4 h1 = *reinterpret_cast<const f32x4*>(basep + 256);
        union { unsigned int w[4]; short8 s; } cv;
        asm("v_cvt_pk_bf16_f32 %0, %1, %2" : "=v"(cv.w[0]) : "v"(h0[0]), "v"(h0[1]));
        asm("v_cvt_pk_bf16_f32 %0, %1, %2" : "=v"(cv.w[1]) : "v"(h0[2]), "v"(h0[3]));
        asm("v_cvt_pk_bf16_f32 %0, %1, %2" : "=v"(cv.w[2]) : "v"(h1[0]), "v"(h1[1]));
        asm("v_cvt_pk_bf16_f32 %0, %1, %2" : "=v"(cv.w[3]) : "v"(h1[2]), "v"(h1[3]));
        af[mf][kh] = cv.s;
      }

    __builtin_amdgcn_s_setprio(1);
    #pragma unroll
    for (int w = 0; w < 3; ++w)
      #pragma unroll
      for (int mf = 0; mf < 4; ++mf) {
        acc[mf][w] = __builtin_amdgcn_mfma_f32_16x16x32_bf16(af[mf][0], wbuf[kt & 1][w][0], acc[mf][w], 0, 0, 0);
        acc[mf][w] = __builtin_amdgcn_mfma_f32_16x16x32_bf16(af[mf][1], wbuf[kt & 1][w][1], acc[mf][w], 0, 0, 0);
      }
    __builtin_amdgcn_s_setprio(0);
  }
  #undef QSTAGE
  #undef WLOAD

  const int h = wave * 16 + lr;
  const int b = m0 >> 11;
  #pragma unroll
  for (int mf = 0; mf < 4; ++mf) {
    int r0 = m0 + mf * 16 + (lane >> 4) * 4;
    #pragma unroll
    for (int j = 0; j < 4; ++j) {
      int r = r0 + j;
      q[(size_t)r * 128 + h] = f2bf(acc[mf][0][j]);
      int rr  = r & 63;
      int nf  = ((rr >> 5) & 1) * 2 + ((rr >> 2) & 1);
      int lrk = ((rr >> 3) & 3) * 4 + (rr & 3);
      size_t kidx = (size_t)(r >> 6) * 8192
                  + (size_t)(((nf * 4 + (h >> 5)) * 64 + ((h >> 3) & 3) * 16 + lrk) * 8 + (h & 7));
      kb[kidx] = f2bf(acc[mf][1][j]);
    }
    int t = r0 & 2047;
    size_t vidx = (size_t)b * 262144 + (size_t)(t >> 6) * 8192
                + (size_t)(((((h >> 4) * 2 + ((t >> 5) & 1)) * 64 + ((t >> 3) & 3) * 16 + (h & 15)) * 8) + (t & 7));
    ushort4 u;
    u.x = f2bf(acc[mf][2][0]); u.y = f2bf(acc[mf][2][1]);
    u.z = f2bf(acc[mf][2][2]); u.w = f2bf(acc[mf][2][3]);
    *reinterpret_cast<ushort4*>(vt + vidx) = u;
  }
}

// ---------------- Kernel 2: causal flash attention v25 (direct L2,
// compiler-proof counted-vmcnt pipeline).
// 512 blocks x 256 thr (4 self-paced waves, bodies s ≡ wv mod 4).
// Phase: issue K(s+4) -> s_waitcnt vmcnt(8) [retires K(s),V(s); K(s+4)
// stays in flight] -> sched_barrier -> body (pure-register) -> issue V(s+4).
template<bool MASK>
static __device__ __forceinline__ void body_regs(
    int s, int myrow0, int myrow1, int lg,
    const short8 (&kf)[2][4], const short8 (&vf)[8],
    const short8 (&qf)[2][4], f32x4 (&o)[2][8], float (&lsum)[2])
{
  const float SC = 0.03125f * 1.44269504f;  // C^-0.5 * log2(e)

  f32x4 sT[2][2];
  __builtin_amdgcn_s_setprio(1);
  #pragma unroll
  for (int g = 0; g < 2; ++g)
    #pragma unroll
    for (int nf = 0; nf < 2; ++nf) {
      sT[g][nf] = (f32x4){0.f, 0.f, 0.f, 0.f};
      #pragma unroll
      for (int ks = 0; ks < 4; ++ks)
        sT[g][nf] = __builtin_amdgcn_mfma_f32_16x16x32_bf16(kf[nf][ks], qf[g][ks], sT[g][nf], 0, 0, 0);
    }
  __builtin_amdgcn_s_setprio(0);

  union { unsigned int w[4]; short8 s8; } cv[2];
  #pragma unroll
  for (int g = 0; g < 2; ++g) {
    const int myrow = g ? myrow1 : myrow0;
    float p[8];
    #pragma unroll
    for (int nf = 0; nf < 2; ++nf)
      #pragma unroll
      for (int j = 0; j < 4; ++j) {
        float sv = sT[g][nf][j] * SC;
        if (MASK) {
          int kv = s * 32 + lg * 8 + nf * 4 + j;
          if (kv > myrow) sv = -1e30f;  // exp2 -> 0
        }
        p[nf * 4 + j] = exp2f(sv);
      }
    lsum[g] += ((p[0] + p[1]) + (p[2] + p[3])) + ((p[4] + p[5]) + (p[6] + p[7]));
    #pragma unroll
    for (int u = 0; u < 4; ++u)
      asm("v_cvt_pk_bf16_f32 %0, %1, %2" : "=v"(cv[g].w[u]) : "v"(p[u * 2]), "v"(p[u * 2 + 1]));
  }

  __builtin_amdgcn_s_setprio(1);
  #pragma unroll
  for (int g = 0; g < 2; ++g)
    #pragma unroll
    for (int n = 0; n < 8; ++n)
      o[g][n] = __builtin_amdgcn_mfma_f32_16x16x32_bf16(vf[n], cv[g].s8, o[g][n], 0, 0, 0);
  __builtin_amdgcn_s_setprio(0);
}

__global__ __launch_bounds__(256, 2) void attn_kernel(
    const unsigned short* __restrict__ q,   // [8][2048][128] row-major
    const unsigned short* __restrict__ kb,  // [256 blk][8192] fragment-major
    const unsigned short* __restrict__ vt,  // [8][32 blk][8192] fragment-major
    float* __restrict__ out)                // [8][2048][128] f32
{
  __shared__ float mb[12672];               // 4-way merge scratch (~50KB)

  const int tid  = threadIdx.x;
  const int lane = tid & 63;
  const int wv   = tid >> 6;                // 0..3: independent KV-split wave
  const int lr = lane & 15;
  const int lg = lane >> 4;
  const int bid = blockIdx.x;
  const int b  = bid & 7;                   // batch -> XCD affinity
  const int g2 = bid >> 3;                  // 0..63
  const int tt = (g2 < 32) ? (63 - g2) : (g2 - 32);   // complementary pairing
  const int t0 = tt * 32;
  const int nb = tt + 1;                    // 32-kv bodies incl. diagonal

  const unsigned short* kbase = kb + (size_t)b * 262144;
  const unsigned short* vbase = vt + (size_t)b * 262144;
  const int myrow0 = t0 + lr;
  const int myrow1 = t0 + 16 + lr;

  short8 qf[2][4];
  #pragma unroll
  for (int g = 0; g < 2; ++g) {
    const unsigned short* qp = q + ((size_t)(b * 2048) + (g ? myrow1 : myrow0)) * 128 + lg * 8;
    #pragma unroll
    for (int ks = 0; ks < 4; ++ks)
      qf[g][ks] = *reinterpret_cast<const short8*>(qp + ks * 32);
  }

  f32x4 o[2][8];
  #pragma unroll
  for (int g = 0; g < 2; ++g)
    #pragma unroll
    for (int n = 0; n < 8; ++n) o[g][n] = (f32x4){0.f, 0.f, 0.f, 0.f};
  float lsum[2] = {0.f, 0.f};

  #define GLOADK(KF, S)                                                          \
    do {                                                                         \
      const unsigned short* kg = kbase + (size_t)((S) >> 1) * 8192 + ((S) & 1) * 4096; \
      _Pragma("unroll")                                                          \
      for (int nf = 0; nf < 2; ++nf)                                             \
        _Pragma("unroll")                                                        \
        for (int ks = 0; ks < 4; ++ks)                                           \
          KF[nf][ks] = *reinterpret_cast<const short8*>(kg + ((nf * 4 + ks) * 64 + lane) * 8); \
    } while (0)

  #define GLOADV(S)                                                              \
    do {                                                                         \
      const unsigned short* vg = vbase + (size_t)((S) >> 1) * 8192;              \
      const int hh = (S) & 1;                                                    \
      _Pragma("unroll")                                                          \
      for (int n = 0; n < 8; ++n)                                                \
        vf[n] = *reinterpret_cast<const short8*>(vg + ((n * 2 + hh) * 64 + lane) * 8); \
    } while (0)

  short8 kfA[2][4], kfB[2][4], vf[8];       // named reg sets (rule #20)

  if (wv < nb) { GLOADK(kfA, wv); GLOADV(wv); }   // 16 outstanding

  // PHASE: issue K(s+4) [8 loads]; counted wait vmcnt(8) retires K(s)+V(s)
  // while K(s+4) stays in flight; body is pure-register; then issue V(s+4).
  #define PHASE(CURK, NXTK)                                                      \
    do {                                                                         \
      if (s + 4 < nb) {                                                          \
        GLOADK(NXTK, s + 4);                                                     \
        asm volatile("s_waitcnt vmcnt(8)" ::: "memory");                         \
      } else {                                                                   \
        asm volatile("s_waitcnt vmcnt(0)" ::: "memory");                         \
      }                                                                          \
      __builtin_amdgcn_sched_barrier(0);                                         \
      if (s == nb - 1)                                                           \
        body_regs<true >(s, myrow0, myrow1, lg, CURK, vf, qf, o, lsum);          \
      else                                                                       \
        body_regs<false>(s, myrow0, myrow1, lg, CURK, vf, qf, o, lsum);          \
      if (s + 4 < nb) GLOADV(s + 4);                                             \
      __builtin_amdgcn_sched_barrier(0);                                         \
    } while (0)

  int s = wv;
  #pragma unroll 1
  while (s < nb) {
    PHASE(kfA, kfB);
    s += 4;
    if (s >= nb) break;
    PHASE(kfB, kfA);
    s += 4;
  }
  #undef PHASE
  #undef GLOADK
  #undef GLOADV

  // ---- exact 4-way additive merge (flat softmax => partials just add).
  __syncthreads();
  if (wv != 0) {
    #pragma unroll
    for (int g = 0; g < 2; ++g)
      #pragma unroll
      for (int n = 0; n < 8; ++n) {
        float4 st;
        st.x = o[g][n][0]; st.y = o[g][n][1]; st.z = o[g][n][2]; st.w = o[g][n][3];
        *reinterpret_cast<float4*>(&mb[(size_t)((wv - 1) * 16 + g * 8 + n) * 256 + lane * 4]) = st;
      }
    mb[12288 + (wv - 1) * 128 + lane]      = lsum[0];
    mb[12288 + (wv - 1) * 128 + 64 + lane] = lsum[1];
  }
  __syncthreads();
  if (wv == 0) {
    #pragma unroll
    for (int g = 0; g < 2; ++g) {
      #pragma unroll
      for (int n = 0; n < 8; ++n) {
        #pragma unroll
        for (int w = 1; w < 4; ++w) {
          float4 ad = *reinterpret_cast<const float4*>(
              &mb[(size_t)((w - 1) * 16 + g * 8 + n) * 256 + lane * 4]);
          o[g][n][0] += ad.x; o[g][n][1] += ad.y; o[g][n][2] += ad.z; o[g][n][3] += ad.w;
        }
      }
      float ps = lsum[g];
      #pragma unroll
      for (int w = 1; w < 4; ++w)
        ps += mb[12288 + (w - 1) * 128 + g * 64 + lane];
      ps += __shfl_xor(ps, 16);
      ps += __shfl_xor(ps, 32);
      float rcp = 1.0f / ps;
      float* op = out + ((size_t)(b * 2048) + (g ? myrow1 : myrow0)) * 128;
      #pragma unroll
      for (int n = 0; n < 8; ++n) {
        float4 st;
        st.x = o[g][n][0] * rcp; st.y = o[g][n][1] * rcp;
        st.z = o[g][n][2] * rcp; st.w = o[g][n][3] * rcp;
        *reinterpret_cast<float4*>(op + n * 16 + lg * 4) = st;
      }
    }
  }
}

extern "C" void kernel_launch(void* const* d_in, const int* in_sizes, int n_in,
                              void* d_out, int out_size, void* d_ws, size_t ws_size,
                              hipStream_t stream) {
  const float* x  = (const float*)d_in[0];
  const float* Wk = (const float*)d_in[1];
  const float* Wq = (const float*)d_in[2];
  const float* Wv = (const float*)d_in[3];
  float* out = (float*)d_out;

  char* ws = (char*)d_ws;
  unsigned short* q  = (unsigned short*)(ws);                  // 4 MB
  unsigned short* kb = (unsigned short*)(ws + (4u  << 20));    // 4 MB (fragment-major)
  unsigned short* vt = (unsigned short*)(ws + (8u  << 20));    // 4 MB (fragment-major)
  unsigned short* Wt = (unsigned short*)(ws + (12u << 20));    // 768 KB (Wt2)

  wtrans_kernel<<<dim3(1536), dim3(256), 0, stream>>>(Wq, Wk, Wv, Wt);
  qkv_kernel<<<dim3(256), dim3(512), 0, stream>>>(x, Wt, q, kb, vt);
  attn_kernel<<<dim3(512), dim3(256), 0, stream>>>(q, kb, vt, out);
}

// Round 26
// 55.480 us; speedup vs baseline: 1.1751x; 1.1751x over previous
//
#include <hip/hip_runtime.h>

// Head forward: q=x@Wq, k=x@Wk, v=x@Wv; out = softmax(causal(q k^T / 32)) @ v
// B=8 T=2048 C=1024 H=128. Inputs f32, output f32, internal bf16 MFMA.
// K and V are stored in FRAGMENT-MAJOR order (16B chunk = (frag)*64 + lane).
// W is stored in Wt2 fragment-major order.
// qkv v18 (BM=64, grid 256, depth-2 counted vmcnt — best measured).
// attn v26: direct-L2, KVBLK=64 — all 32 K+V loads issued per phase as one
// batch; verified 64-kv body math; compiler-scheduled waits (R23 style).

typedef __attribute__((ext_vector_type(8))) short short8;
typedef __attribute__((ext_vector_type(4))) float f32x4;

typedef const __attribute__((address_space(1))) unsigned int* gas_u32p;
typedef __attribute__((address_space(3))) unsigned int* las_u32p;

static __device__ __forceinline__ unsigned short f2bf(float f) {
  unsigned int u = __float_as_uint(f);
  u += 0x7FFF + ((u >> 16) & 1);      // round-to-nearest-even
  return (unsigned short)(u >> 16);
}

// ---------------- Kernel 0: Wt2 fragment-major weight transpose+convert.
__global__ void wtrans_kernel(const float* __restrict__ Wq,
                              const float* __restrict__ Wk,
                              const float* __restrict__ Wv,
                              unsigned short* __restrict__ Wt) {
  int idx = blockIdx.x * blockDim.x + threadIdx.x;   // 0 .. 3*128*1024-1
  int C  = idx >> 3;
  int e  = idx & 7;
  int l  = C & 63;
  int t1 = C >> 6;
  int kh = t1 & 1;
  int t2 = t1 >> 1;
  int w  = t2 % 3;
  int t3 = t2 / 3;
  int wave = t3 & 7;
  int kt   = t3 >> 3;
  int n = wave * 16 + (l & 15);
  int k = kt * 64 + kh * 32 + (l >> 4) * 8 + e;
  const float* W = (w == 0) ? Wq : (w == 1) ? Wk : Wv;
  Wt[idx] = f2bf(W[k * 128 + n]);
}

// ---------------- Kernel 1: fused QKV GEMM (v18: BM=64, grid 256, depth-2).
__global__ __launch_bounds__(512) void qkv_kernel(
    const float* __restrict__ x,            // [16384][1024] f32
    const unsigned short* __restrict__ Wt,  // Wt2 fragment-major bf16
    unsigned short* __restrict__ q,         // [16384][128] bf16 (row-major)
    unsigned short* __restrict__ kb,        // [256 blk][8192] bf16 fragment-major
    unsigned short* __restrict__ vt)        // [8][32 blk][8192] bf16 fragment-major
{
  __shared__ float xl[4][4096];         // 4 x 16KB x-tiles, fragment-major
  const int tid  = threadIdx.x;
  const int lane = tid & 63;
  const int wave = tid >> 6;            // 0..7
  const int m0   = blockIdx.x * 64;
  const int lr   = lane & 15;

  f32x4 acc[4][3];
  #pragma unroll
  for (int i = 0; i < 4; ++i)
    #pragma unroll
    for (int w = 0; w < 3; ++w) acc[i][w] = (f32x4){0.f, 0.f, 0.f, 0.f};

  int srow[2], skq[2];
  #pragma unroll
  for (int i = 0; i < 2; ++i) {
    int c  = i * 512 + tid;
    int ln = c & 63;
    int g  = c >> 6;
    srow[i] = (g >> 2) * 16 + (ln & 15);
    skq[i]  = ((g >> 1) & 1) * 8 + (ln >> 4) * 2 + (g & 1);
  }

  #define QSTAGE(KT, BUF)                                                        \
    do {                                                                         \
      _Pragma("unroll")                                                          \
      for (int i = 0; i < 2; ++i) {                                              \
        const float* gsrc = x + (size_t)(m0 + srow[i]) * 1024 + (KT) * 64 + skq[i] * 4; \
        __builtin_amdgcn_global_load_lds((gas_u32p)gsrc,                         \
            (las_u32p)&xl[BUF][(i * 512 + tid) * 4], 16, 0, 0);                  \
      }                                                                          \
    } while (0)

  const unsigned short* w2base = Wt + wave * 3072 + lane * 8;

  #define WLOAD(KT, DST)                                                         \
    do {                                                                         \
      _Pragma("unroll")                                                          \
      for (int w = 0; w < 3; ++w) {                                              \
        DST[w][0] = *reinterpret_cast<const short8*>(w2base + (KT) * 24576 + w * 1024);       \
        DST[w][1] = *reinterpret_cast<const short8*>(w2base + (KT) * 24576 + w * 1024 + 512); \
      }                                                                          \
    } while (0)

  short8 wbuf[2][3][2];

  WLOAD(0, wbuf[0]);
  QSTAGE(0, 0);
  QSTAGE(1, 1);

  #pragma unroll
  for (int kt = 0; kt < 16; ++kt) {
    if (kt < 15) WLOAD(kt + 1, wbuf[(kt + 1) & 1]);
    if (kt < 14) QSTAGE(kt + 2, (kt + 2) & 3);
    if (kt < 14)      asm volatile("s_waitcnt vmcnt(10)" ::: "memory");
    else if (kt < 15) asm volatile("s_waitcnt vmcnt(8)"  ::: "memory");
    else              asm volatile("s_waitcnt vmcnt(0)"  ::: "memory");
    __builtin_amdgcn_sched_barrier(0);
    __builtin_amdgcn_s_barrier();       // single barrier per step

    short8 af[4][2];
    #pragma unroll
    for (int mf = 0; mf < 4; ++mf)
      #pragma unroll
      for (int kh = 0; kh < 2; ++kh) {
        const float* basep = &xl[kt & 3][((mf * 2 + kh) * 2) * 256 + lane * 4];
        f32x4 h0 = *reinterpret_cast<const f32x4*>(basep);
        f32x4 h1 = *reinterpret_cast<const f32x4*>(basep + 256);
        union { unsigned int w[4]; short8 s; } cv;
        asm("v_cvt_pk_bf16_f32 %0, %1, %2" : "=v"(cv.w[0]) : "v"(h0[0]), "v"(h0[1]));
        asm("v_cvt_pk_bf16_f32 %0, %1, %2" : "=v"(cv.w[1]) : "v"(h0[2]), "v"(h0[3]));
        asm("v_cvt_pk_bf16_f32 %0, %1, %2" : "=v"(cv.w[2]) : "v"(h1[0]), "v"(h1[1]));
        asm("v_cvt_pk_bf16_f32 %0, %1, %2" : "=v"(cv.w[3]) : "v"(h1[2]), "v"(h1[3]));
        af[mf][kh] = cv.s;
      }

    __builtin_amdgcn_s_setprio(1);
    #pragma unroll
    for (int w = 0; w < 3; ++w)
      #pragma unroll
      for (int mf = 0; mf < 4; ++mf) {
        acc[mf][w] = __builtin_amdgcn_mfma_f32_16x16x32_bf16(af[mf][0], wbuf[kt & 1][w][0], acc[mf][w], 0, 0, 0);
        acc[mf][w] = __builtin_amdgcn_mfma_f32_16x16x32_bf16(af[mf][1], wbuf[kt & 1][w][1], acc[mf][w], 0, 0, 0);
      }
    __builtin_amdgcn_s_setprio(0);
  }
  #undef QSTAGE
  #undef WLOAD

  const int h = wave * 16 + lr;
  const int b = m0 >> 11;
  #pragma unroll
  for (int mf = 0; mf < 4; ++mf) {
    int r0 = m0 + mf * 16 + (lane >> 4) * 4;
    #pragma unroll
    for (int j = 0; j < 4; ++j) {
      int r = r0 + j;
      q[(size_t)r * 128 + h] = f2bf(acc[mf][0][j]);
      int rr  = r & 63;
      int nf  = ((rr >> 5) & 1) * 2 + ((rr >> 2) & 1);
      int lrk = ((rr >> 3) & 3) * 4 + (rr & 3);
      size_t kidx = (size_t)(r >> 6) * 8192
                  + (size_t)(((nf * 4 + (h >> 5)) * 64 + ((h >> 3) & 3) * 16 + lrk) * 8 + (h & 7));
      kb[kidx] = f2bf(acc[mf][1][j]);
    }
    int t = r0 & 2047;
    size_t vidx = (size_t)b * 262144 + (size_t)(t >> 6) * 8192
                + (size_t)(((((h >> 4) * 2 + ((t >> 5) & 1)) * 64 + ((t >> 3) & 3) * 16 + (h & 15)) * 8) + (t & 7));
    ushort4 u;
    u.x = f2bf(acc[mf][2][0]); u.y = f2bf(acc[mf][2][1]);
    u.z = f2bf(acc[mf][2][2]); u.w = f2bf(acc[mf][2][3]);
    *reinterpret_cast<ushort4*>(vt + vidx) = u;
  }
}

// ---------------- Kernel 2: causal flash attention v26 (direct L2, KVBLK=64).
// 512 blocks (64 x 32-row tiles, complementary-paired, x 8 batches) x 256 thr
// (4 self-paced waves; wave wv handles 64-kv bodies s ≡ wv mod 4,
// nb = (tt>>1)+1). Per phase: issue all 32 K+V loads (one L2 round-trip,
// compiler places waits at first use), then verified 64-kv body:
// value (nf,j) is kv = s*64 + (nf>>1)*32 + lg*8 + (nf&1)*4 + j.
template<bool MASK>
static __device__ __forceinline__ void body64(
    int s, int myrow0, int myrow1, int lg,
    const short8 (&kf)[4][4], const short8 (&vf)[8][2],
    const short8 (&qf)[2][4], f32x4 (&o)[2][8], float (&lsum)[2])
{
  const float SC = 0.03125f * 1.44269504f;  // C^-0.5 * log2(e)

  f32x4 sT[2][4];
  __builtin_amdgcn_s_setprio(1);
  #pragma unroll
  for (int g = 0; g < 2; ++g)
    #pragma unroll
    for (int nf = 0; nf < 4; ++nf) {
      sT[g][nf] = (f32x4){0.f, 0.f, 0.f, 0.f};
      #pragma unroll
      for (int ks = 0; ks < 4; ++ks)
        sT[g][nf] = __builtin_amdgcn_mfma_f32_16x16x32_bf16(kf[nf][ks], qf[g][ks], sT[g][nf], 0, 0, 0);
    }
  __builtin_amdgcn_s_setprio(0);

  unsigned int pk[2][8];
  #pragma unroll
  for (int g = 0; g < 2; ++g) {
    const int myrow = g ? myrow1 : myrow0;
    float p[16];
    #pragma unroll
    for (int nf = 0; nf < 4; ++nf)
      #pragma unroll
      for (int j = 0; j < 4; ++j) {
        float sv = sT[g][nf][j] * SC;
        if (MASK) {
          int kv = s * 64 + (nf >> 1) * 32 + lg * 8 + (nf & 1) * 4 + j;
          if (kv > myrow) sv = -1e30f;  // exp2 -> 0
        }
        p[nf * 4 + j] = exp2f(sv);
      }
    {
      float s0 = (p[0] + p[1]) + (p[2] + p[3]);
      float s1 = (p[4] + p[5]) + (p[6] + p[7]);
      float s2 = (p[8] + p[9]) + (p[10] + p[11]);
      float s3 = (p[12] + p[13]) + (p[14] + p[15]);
      lsum[g] += (s0 + s1) + (s2 + s3);
    }
    #pragma unroll
    for (int u = 0; u < 8; ++u)
      asm("v_cvt_pk_bf16_f32 %0, %1, %2" : "=v"(pk[g][u]) : "v"(p[u * 2]), "v"(p[u * 2 + 1]));
  }

  __builtin_amdgcn_s_setprio(1);
  #pragma unroll
  for (int ks = 0; ks < 2; ++ks)
    #pragma unroll
    for (int g = 0; g < 2; ++g) {
      union { unsigned int w[4]; short8 s8; } cv;
      cv.w[0] = pk[g][ks * 4 + 0]; cv.w[1] = pk[g][ks * 4 + 1];
      cv.w[2] = pk[g][ks * 4 + 2]; cv.w[3] = pk[g][ks * 4 + 3];
      #pragma unroll
      for (int n = 0; n < 8; ++n)
        o[g][n] = __builtin_amdgcn_mfma_f32_16x16x32_bf16(vf[n][ks], cv.s8, o[g][n], 0, 0, 0);
    }
  __builtin_amdgcn_s_setprio(0);
}

__global__ __launch_bounds__(256, 2) void attn_kernel(
    const unsigned short* __restrict__ q,   // [8][2048][128] row-major
    const unsigned short* __restrict__ kb,  // [256 blk][8192] fragment-major
    const unsigned short* __restrict__ vt,  // [8][32 blk][8192] fragment-major
    float* __restrict__ out)                // [8][2048][128] f32
{
  __shared__ float mb[12672];               // 4-way merge scratch (~50KB)

  const int tid  = threadIdx.x;
  const int lane = tid & 63;
  const int wv   = tid >> 6;                // 0..3: independent KV-split wave
  const int lr = lane & 15;
  const int lg = lane >> 4;
  const int bid = blockIdx.x;
  const int b  = bid & 7;                   // batch -> XCD affinity
  const int g2 = bid >> 3;                  // 0..63
  const int tt = (g2 < 32) ? (63 - g2) : (g2 - 32);   // complementary pairing
  const int t0 = tt * 32;
  const int nb = (tt >> 1) + 1;             // 64-kv bodies incl. diagonal

  const unsigned short* kbase = kb + (size_t)b * 262144;
  const unsigned short* vbase = vt + (size_t)b * 262144;
  const int myrow0 = t0 + lr;
  const int myrow1 = t0 + 16 + lr;

  short8 qf[2][4];
  #pragma unroll
  for (int g = 0; g < 2; ++g) {
    const unsigned short* qp = q + ((size_t)(b * 2048) + (g ? myrow1 : myrow0)) * 128 + lg * 8;
    #pragma unroll
    for (int ks = 0; ks < 4; ++ks)
      qf[g][ks] = *reinterpret_cast<const short8*>(qp + ks * 32);
  }

  f32x4 o[2][8];
  #pragma unroll
  for (int g = 0; g < 2; ++g)
    #pragma unroll
    for (int n = 0; n < 8; ++n) o[g][n] = (f32x4){0.f, 0.f, 0.f, 0.f};
  float lsum[2] = {0.f, 0.f};

  short8 kf[4][4], vf[8][2];

  #pragma unroll 1
  for (int s = wv; s < nb; s += 4) {
    // issue all 32 K+V loads (one batched L2 round-trip)
    {
      const unsigned short* kg = kbase + (size_t)s * 8192;
      const unsigned short* vg = vbase + (size_t)s * 8192;
      #pragma unroll
      for (int nf = 0; nf < 4; ++nf)
        #pragma unroll
        for (int ks = 0; ks < 4; ++ks)
          kf[nf][ks] = *reinterpret_cast<const short8*>(kg + ((nf * 4 + ks) * 64 + lane) * 8);
      #pragma unroll
      for (int n = 0; n < 8; ++n)
        #pragma unroll
        for (int ks = 0; ks < 2; ++ks)
          vf[n][ks] = *reinterpret_cast<const short8*>(vg + ((n * 2 + ks) * 64 + lane) * 8);
    }
    if (s == nb - 1)
      body64<true >(s, myrow0, myrow1, lg, kf, vf, qf, o, lsum);
    else
      body64<false>(s, myrow0, myrow1, lg, kf, vf, qf, o, lsum);
  }

  // ---- exact 4-way additive merge (flat softmax => partials just add).
  __syncthreads();
  if (wv != 0) {
    #pragma unroll
    for (int g = 0; g < 2; ++g)
      #pragma unroll
      for (int n = 0; n < 8; ++n) {
        float4 st;
        st.x = o[g][n][0]; st.y = o[g][n][1]; st.z = o[g][n][2]; st.w = o[g][n][3];
        *reinterpret_cast<float4*>(&mb[(size_t)((wv - 1) * 16 + g * 8 + n) * 256 + lane * 4]) = st;
      }
    mb[12288 + (wv - 1) * 128 + lane]      = lsum[0];
    mb[12288 + (wv - 1) * 128 + 64 + lane] = lsum[1];
  }
  __syncthreads();
  if (wv == 0) {
    #pragma unroll
    for (int g = 0; g < 2; ++g) {
      #pragma unroll
      for (int n = 0; n < 8; ++n) {
        #pragma unroll
        for (int w = 1; w < 4; ++w) {
          float4 ad = *reinterpret_cast<const float4*>(
              &mb[(size_t)((w - 1) * 16 + g * 8 + n) * 256 + lane * 4]);
          o[g][n][0] += ad.x; o[g][n][1] += ad.y; o[g][n][2] += ad.z; o[g][n][3] += ad.w;
        }
      }
      float ps = lsum[g];
      #pragma unroll
      for (int w = 1; w < 4; ++w)
        ps += mb[12288 + (w - 1) * 128 + g * 64 + lane];
      ps += __shfl_xor(ps, 16);
      ps += __shfl_xor(ps, 32);
      float rcp = 1.0f / ps;
      float* op = out + ((size_t)(b * 2048) + (g ? myrow1 : myrow0)) * 128;
      #pragma unroll
      for (int n = 0; n < 8; ++n) {
        float4 st;
        st.x = o[g][n][0] * rcp; st.y = o[g][n][1] * rcp;
        st.z = o[g][n][2] * rcp; st.w = o[g][n][3] * rcp;
        *reinterpret_cast<float4*>(op + n * 16 + lg * 4) = st;
      }
    }
  }
}

extern "C" void kernel_launch(void* const* d_in, const int* in_sizes, int n_in,
                              void* d_out, int out_size, void* d_ws, size_t ws_size,
                              hipStream_t stream) {
  const float* x  = (const float*)d_in[0];
  const float* Wk = (const float*)d_in[1];
  const float* Wq = (const float*)d_in[2];
  const float* Wv = (const float*)d_in[3];
  float* out = (float*)d_out;

  char* ws = (char*)d_ws;
  unsigned short* q  = (unsigned short*)(ws);                  // 4 MB
  unsigned short* kb = (unsigned short*)(ws + (4u  << 20));    // 4 MB (fragment-major)
  unsigned short* vt = (unsigned short*)(ws + (8u  << 20));    // 4 MB (fragment-major)
  unsigned short* Wt = (unsigned short*)(ws + (12u << 20));    // 768 KB (Wt2)

  wtrans_kernel<<<dim3(1536), dim3(256), 0, stream>>>(Wq, Wk, Wv, Wt);
  qkv_kernel<<<dim3(256), dim3(512), 0, stream>>>(x, Wt, q, kb, vt);
  attn_kernel<<<dim3(512), dim3(256), 0, stream>>>(q, kb, vt, out);
}